// Round 9
// baseline (170.054 us; speedup 1.0000x reference)
//
#include <hip/hip_runtime.h>
#include <hip/hip_fp16.h>
#include <math.h>

#define BATCH 131072
#define NSTEPS 256
#define LOGLO -16.0f
#define LOGSPAN 26.0f
#define LGN 10
#define NPTS 1024          // (1 << LGN)

using f32x2 = __attribute__((ext_vector_type(2))) float;

__device__ __forceinline__ float fast_exp(float x) {
    return __builtin_amdgcn_exp2f(x * 1.44269504088896340736f);
}
__device__ __forceinline__ float fast_rcp(float x) {
    return __builtin_amdgcn_rcpf(x);
}
__device__ __forceinline__ float sigmoidf_fast(float x) {
    return fast_rcp(1.0f + fast_exp(-x));
}

#define REP32(M) M(0) M(1) M(2) M(3) M(4) M(5) M(6) M(7) \
                 M(8) M(9) M(10) M(11) M(12) M(13) M(14) M(15) \
                 M(16) M(17) M(18) M(19) M(20) M(21) M(22) M(23) \
                 M(24) M(25) M(26) M(27) M(28) M(29) M(30) M(31)

#define REP16(M) M(0) M(1) M(2) M(3) M(4) M(5) M(6) M(7) \
                 M(8) M(9) M(10) M(11) M(12) M(13) M(14) M(15)

// Shared MLP+tangent body (see R4). Produces h and pre-sigmoid tangent acc.
#define MLP_BODY(W1r, B1, W2r, B2, W3r, b3v, t, s, sd, H, HACC) \
    { \
        const float __t = (t), __s = (s), __sd = (sd); \
        f32x2 acc2 = {(b3v), 0.0f}; \
        REP32(MLP_L1) \
        REP32(MLP_ROW) \
        H = sigmoidf_fast(acc2.x); \
        HACC = acc2.y; \
    }

#define MLP_L1(j) f32x2 at##j; { \
    const float2 wv = W1r[j]; \
    const float z  = fmaf(wv.x, __t, fmaf(wv.y, __s, B1[j])); \
    const float zd = wv.y * __sd; \
    const float sg = sigmoidf_fast(z); \
    const float da = sg * (1.0f + z * (1.0f - sg)); \
    at##j = (f32x2){z * sg, da * zd}; }

#define MLP_ROW(j) { \
    const float4 q0 = W2r[(j) * 8 + 0]; \
    const float4 q1 = W2r[(j) * 8 + 1]; \
    const float4 q2 = W2r[(j) * 8 + 2]; \
    const float4 q3 = W2r[(j) * 8 + 3]; \
    const float4 q4 = W2r[(j) * 8 + 4]; \
    const float4 q5 = W2r[(j) * 8 + 5]; \
    const float4 q6 = W2r[(j) * 8 + 6]; \
    const float4 q7 = W2r[(j) * 8 + 7]; \
    f32x2 zza = {B2[j], 0.0f}; \
    f32x2 zzb = {0.0f, 0.0f}; \
    zza += (f32x2){q0.x, q0.x} * at0;  zzb += (f32x2){q0.y, q0.y} * at1; \
    zza += (f32x2){q0.z, q0.z} * at2;  zzb += (f32x2){q0.w, q0.w} * at3; \
    zza += (f32x2){q1.x, q1.x} * at4;  zzb += (f32x2){q1.y, q1.y} * at5; \
    zza += (f32x2){q1.z, q1.z} * at6;  zzb += (f32x2){q1.w, q1.w} * at7; \
    zza += (f32x2){q2.x, q2.x} * at8;  zzb += (f32x2){q2.y, q2.y} * at9; \
    zza += (f32x2){q2.z, q2.z} * at10; zzb += (f32x2){q2.w, q2.w} * at11; \
    zza += (f32x2){q3.x, q3.x} * at12; zzb += (f32x2){q3.y, q3.y} * at13; \
    zza += (f32x2){q3.z, q3.z} * at14; zzb += (f32x2){q3.w, q3.w} * at15; \
    zza += (f32x2){q4.x, q4.x} * at16; zzb += (f32x2){q4.y, q4.y} * at17; \
    zza += (f32x2){q4.z, q4.z} * at18; zzb += (f32x2){q4.w, q4.w} * at19; \
    zza += (f32x2){q5.x, q5.x} * at20; zzb += (f32x2){q5.y, q5.y} * at21; \
    zza += (f32x2){q5.z, q5.z} * at22; zzb += (f32x2){q5.w, q5.w} * at23; \
    zza += (f32x2){q6.x, q6.x} * at24; zzb += (f32x2){q6.y, q6.y} * at25; \
    zza += (f32x2){q6.z, q6.z} * at26; zzb += (f32x2){q6.w, q6.w} * at27; \
    zza += (f32x2){q7.x, q7.x} * at28; zzb += (f32x2){q7.y, q7.y} * at29; \
    zza += (f32x2){q7.z, q7.z} * at30; zzb += (f32x2){q7.w, q7.w} * at31; \
    const f32x2 zzt = zza + zzb; \
    const float zv  = zzt.x; \
    const float sg  = sigmoidf_fast(zv); \
    const float da  = sg * (1.0f + zv * (1.0f - sg)); \
    const float w3  = W3r[j]; \
    acc2 += (f32x2){w3, w3} * (f32x2){zv * sg, da * zzt.y}; \
}

// ---------------------------------------------------------------------------
// Kernel 1: paired-entry table.  T2[st][k] = uint2{ half2{h,q}(k),
// half2{h,q}(k+1) } at s = 2^(lo+k*dx), q = s*dh/ds.  One aligned 8B load
// fetches both interpolation endpoints.  Built via LDS handoff so each grid
// point is evaluated once (lane 255 computes the +1 boundary).
// ---------------------------------------------------------------------------
__global__ __launch_bounds__(256) void table_kernel(
    const float* __restrict__ ts,
    const float* __restrict__ W1, const float* __restrict__ b1,
    const float* __restrict__ W2, const float* __restrict__ b2,
    const float* __restrict__ W3, const float* __restrict__ b3,
    uint2* __restrict__ T2, float lo, float dx)
{
    __shared__ __align__(16) float sW1[64];
    __shared__ float sb1[32];
    __shared__ __align__(16) float sW2[1024];
    __shared__ float sb2[32];
    __shared__ float sW3[32];
    __shared__ float sb3[1];
    __shared__ unsigned int sval[257];   // packed half2{h,q} per k

    const int tid = threadIdx.x;
    for (int i = tid; i < 1024; i += 256) sW2[i] = W2[i];
    if (tid < 64) sW1[tid] = W1[tid];
    if (tid < 32) { sb1[tid] = b1[tid]; sb2[tid] = b2[tid]; sW3[tid] = W3[tid]; }
    if (tid == 0) sb3[0] = b3[0];
    __syncthreads();

    const float2* W1r = (const float2*)sW1;
    const float*  B1  = sb1;
    const float4* W2r = (const float4*)sW2;
    const float*  B2  = sb2;
    const float*  W3r = sW3;
    const float   b3v = sb3[0];

    const int gid = blockIdx.x * 256 + tid;
    const int st = gid >> LGN;
    const int k  = gid & (NPTS - 1);

    const float t = ts[st];
    const float s = __builtin_amdgcn_exp2f(fmaf((float)k, dx, lo));

    float h, hacc;
    MLP_BODY(W1r, B1, W2r, B2, W3r, b3v, t, s, 1.0f, h, hacc)
    {
        const float q = h * (1.0f - h) * hacc * s;   // s * dh/ds
        __half2 p = __floats2half2_rn(h, q);
        sval[tid] = *(unsigned int*)&p;
    }

    if (tid == 255) {
        // boundary point k+1 (unused garbage when k+1 == NPTS; i0 <= NPTS-2)
        const float s2 = __builtin_amdgcn_exp2f(fmaf((float)(k + 1), dx, lo));
        float h2, hacc2;
        MLP_BODY(W1r, B1, W2r, B2, W3r, b3v, t, s2, 1.0f, h2, hacc2)
        const float q2 = h2 * (1.0f - h2) * hacc2 * s2;
        __half2 p2 = __floats2half2_rn(h2, q2);
        sval[256] = *(unsigned int*)&p2;
    }
    __syncthreads();

    T2[gid] = make_uint2(sval[tid], sval[tid + 1]);
}

// ---------------------------------------------------------------------------
// Kernel 2: SDE path integration.  16-step chunks: s-recurrence runs ahead
// issuing 16 paired 8B gathers + 16 noise prefetches before any consume --
// memory ILP hides L2 gather latency (TLP is grid-capped at 2 waves/SIMD).
// ---------------------------------------------------------------------------
__global__ __launch_bounds__(256, 2) void path_kernel(
    const float* __restrict__ noise,   // (NSTEPS, BATCH)
    const float* __restrict__ ts,      // (NSTEPS+1)
    const float* __restrict__ wq,      // scalar
    const uint2* __restrict__ T2,      // (NSTEPS, NPTS) paired entries
    float lo, float invdx,
    float* __restrict__ out)           // (BATCH)
{
    __shared__ float2 sdt[NSTEPS];
    const int tid = threadIdx.x;
    if (tid < NSTEPS) {
        const float dtv = ts[tid + 1] - ts[tid];
        sdt[tid] = make_float2(dtv, __builtin_sqrtf(dtv));
    }
    __syncthreads();

    const int gid = blockIdx.x * 256 + tid;
    const float* np_ = noise + gid;
    const float umax = (float)(NPTS - 1) - 0.001f;

    float s   = 1.0f;
    float pnl = 0.0f;

    // preload chunk 0 noise (16 values)
    #define NLD0(k) float n##k = np_[(size_t)(k) * BATCH];
    REP16(NLD0)
    #undef NLD0

    #pragma unroll 1
    for (int c = 0; c < NSTEPS / 16; ++c) {
        const int base = c * 16;

        // prefetch next chunk's noise (uniform branch, loads issued early)
        const float* nb = np_ + ((size_t)base + 16) * BATCH;
        #define NDCL(k) float m##k;
        REP16(NDCL)
        #undef NDCL
        if (c < NSTEPS / 16 - 1) {
            #define NPF(k) m##k = nb[(size_t)(k) * BATCH];
            REP16(NPF)
            #undef NPF
        } else {
            #define NZR(k) m##k = 0.0f;
            REP16(NZR)
            #undef NZR
        }

        // s-chain (cheap, serial) + issue all 16 paired gathers
        #define CH(k) \
            const float2 dts##k = sdt[base + k]; \
            const float dW##k   = n##k * dts##k.y; \
            const float mil##k  = 0.5f * fmaf(dW##k, dW##k, -dts##k.x); \
            const float sum1##k = dts##k.x + dW##k; \
            const float sv##k   = s; \
            s = fmaf(s, sum1##k + mil##k, s); \
            const float x##k = __builtin_amdgcn_logf(sv##k); \
            const float u##k = fminf(fmaxf((x##k - lo) * invdx, 0.0f), umax); \
            const int   i0##k = (int)u##k; \
            const float f##k  = u##k - (float)i0##k; \
            const uint2 E##k = T2[((size_t)(base + k) << LGN) + i0##k];
        REP16(CH)
        #undef CH

        // consume gathers into pnl
        #define PN(k) { \
            const float2 a0 = __half22float2(*(const __half2*)&E##k.x); \
            const float2 a1 = __half22float2(*(const __half2*)&E##k.y); \
            const float h  = fmaf(f##k, a1.x - a0.x, a0.x); \
            const float q  = fmaf(f##k, a1.y - a0.y, a0.y); \
            const float g1  = sv##k * h; \
            const float dg1 = fmaf(sv##k, q, g1); \
            pnl = fmaf(dg1, mil##k, fmaf(g1, sum1##k, pnl)); }
        REP16(PN)
        #undef PN

        // rotate prefetched noise into place
        #define NRT(k) n##k = m##k;
        REP16(NRT)
        #undef NRT
    }

    const float z = fmaxf(0.0f, s - 3.0f);
    const float d = z - pnl - wq[0];
    out[gid] = d * d;
}

// ---------------------------------------------------------------------------
// Fallback: direct per-thread MLP evaluation (R4 kernel) if ws too small.
// ---------------------------------------------------------------------------
__global__ __launch_bounds__(256, 3) void deep_hedging_direct(
    const float* __restrict__ noise, const float* __restrict__ ts,
    const float* __restrict__ w,
    const float* __restrict__ W1, const float* __restrict__ b1,
    const float* __restrict__ W2, const float* __restrict__ b2,
    const float* __restrict__ W3, const float* __restrict__ b3,
    float* __restrict__ out)
{
    __shared__ __align__(16) float sW1[64];
    __shared__ float sb1[32];
    __shared__ __align__(16) float sW2[1024];
    __shared__ float sb2[32];
    __shared__ float sW3[32];
    __shared__ float sb3w[2];
    __shared__ float sts[NSTEPS + 1];

    const int tid = threadIdx.x;
    for (int i = tid; i < 1024; i += 256) sW2[i] = W2[i];
    if (tid < 64) sW1[tid] = W1[tid];
    if (tid < 32) { sb1[tid] = b1[tid]; sb2[tid] = b2[tid]; sW3[tid] = W3[tid]; }
    if (tid == 0) { sb3w[0] = b3[0]; sb3w[1] = w[0]; }
    for (int i = tid; i < NSTEPS + 1; i += 256) sts[i] = ts[i];
    __syncthreads();

    const int gid = blockIdx.x * 256 + tid;
    const float* np_ = noise + gid;

    float s   = 1.0f;
    float pnl = 0.0f;
    const float b3v = sb3w[0];
    const float wv_ = sb3w[1];

    #pragma unroll 1
    for (int st = 0; st < NSTEPS; ++st) {
        int zr = 0;
        asm volatile("" : "+v"(zr));   // block LICM of weight loads
        const float2* W1r = (const float2*)sW1 + zr;
        const float*  B1  = sb1 + zr;
        const float4* W2r = (const float4*)sW2 + zr;
        const float*  B2  = sb2 + zr;
        const float*  W3r = sW3 + zr;

        const float t  = sts[st];
        const float dt = sts[st + 1] - t;
        const float dW = np_[(size_t)st * BATCH] * __builtin_sqrtf(dt);
        const float sd = s;

        float h, hacc;
        MLP_BODY(W1r, B1, W2r, B2, W3r, b3v, t, s, sd, h, hacc)
        const float hd = h * (1.0f - h) * hacc;

        const float mil = 0.5f * (dW * dW - dt);
        const float g1  = s * h;
        const float dg1 = fmaf(sd, h, s * hd);
        const float snew = s + s * dt + s * dW + sd * mil;
        pnl = pnl + g1 * dt + g1 * dW + dg1 * mil;
        s = snew;
    }

    const float z = fmaxf(0.0f, s - 3.0f);
    const float d = z - pnl - wv_;
    out[gid] = d * d;
}

extern "C" void kernel_launch(void* const* d_in, const int* in_sizes, int n_in,
                              void* d_out, int out_size, void* d_ws, size_t ws_size,
                              hipStream_t stream) {
    const float* noise = (const float*)d_in[0];
    const float* ts    = (const float*)d_in[1];
    const float* w     = (const float*)d_in[2];
    const float* W1    = (const float*)d_in[3];
    const float* b1    = (const float*)d_in[4];
    const float* W2    = (const float*)d_in[5];
    const float* b2    = (const float*)d_in[6];
    const float* W3    = (const float*)d_in[7];
    const float* b3    = (const float*)d_in[8];
    float* out = (float*)d_out;

    const size_t need = (size_t)NSTEPS * NPTS * sizeof(uint2);   // 2 MB

    if (ws_size >= need) {
        const float dx = LOGSPAN / (float)NPTS;
        const float invdx = (float)NPTS / LOGSPAN;
        uint2* T2 = (uint2*)d_ws;

        dim3 tb(256), tg((NSTEPS * NPTS) / 256);
        table_kernel<<<tg, tb, 0, stream>>>(ts, W1, b1, W2, b2, W3, b3,
                                            T2, LOGLO, dx);
        dim3 pb(256), pg(BATCH / 256);
        path_kernel<<<pg, pb, 0, stream>>>(noise, ts, w, T2, LOGLO,
                                           invdx, out);
    } else {
        dim3 grid(BATCH / 256), block(256);
        deep_hedging_direct<<<grid, block, 0, stream>>>(noise, ts, w, W1, b1,
                                                        W2, b2, W3, b3, out);
    }
}

// Round 10
// 76.799 us; speedup vs baseline: 2.2143x; 2.2143x over previous
//
#include <hip/hip_runtime.h>
#include <hip/hip_fp16.h>
#include <math.h>

#define BATCH 131072
#define NSTEPS 256
#define LGN 10
#define NPTS 1024          // (1 << LGN)
#define ZSPAN 16.0f        // z in [-8, 8]
#define ZSCALE 64.0f       // NPTS / ZSPAN
#define DZ 0.015625f       // ZSPAN / NPTS
#define MU_C 0.72134752044448170367f   // (mu - sigma^2/2)/ln2 = 0.5/ln2
#define SD_C 1.4426950408889634f       // sigma/ln2

using f32x2 = __attribute__((ext_vector_type(2))) float;

__device__ __forceinline__ float fast_exp(float x) {
    return __builtin_amdgcn_exp2f(x * 1.44269504088896340736f);
}
__device__ __forceinline__ float fast_rcp(float x) {
    return __builtin_amdgcn_rcpf(x);
}
__device__ __forceinline__ float sigmoidf_fast(float x) {
    return fast_rcp(1.0f + fast_exp(-x));
}

#define REP32(M) M(0) M(1) M(2) M(3) M(4) M(5) M(6) M(7) \
                 M(8) M(9) M(10) M(11) M(12) M(13) M(14) M(15) \
                 M(16) M(17) M(18) M(19) M(20) M(21) M(22) M(23) \
                 M(24) M(25) M(26) M(27) M(28) M(29) M(30) M(31)

#define REP16(M) M(0) M(1) M(2) M(3) M(4) M(5) M(6) M(7) \
                 M(8) M(9) M(10) M(11) M(12) M(13) M(14) M(15)

// Shared MLP+tangent body (see R4). Produces h and pre-sigmoid tangent acc.
#define MLP_BODY(W1r, B1, W2r, B2, W3r, b3v, t, s, sd, H, HACC) \
    { \
        const float __t = (t), __s = (s), __sd = (sd); \
        f32x2 acc2 = {(b3v), 0.0f}; \
        REP32(MLP_L1) \
        REP32(MLP_ROW) \
        H = sigmoidf_fast(acc2.x); \
        HACC = acc2.y; \
    }

#define MLP_L1(j) f32x2 at##j; { \
    const float2 wv = W1r[j]; \
    const float z  = fmaf(wv.x, __t, fmaf(wv.y, __s, B1[j])); \
    const float zd = wv.y * __sd; \
    const float sg = sigmoidf_fast(z); \
    const float da = sg * (1.0f + z * (1.0f - sg)); \
    at##j = (f32x2){z * sg, da * zd}; }

#define MLP_ROW(j) { \
    const float4 q0 = W2r[(j) * 8 + 0]; \
    const float4 q1 = W2r[(j) * 8 + 1]; \
    const float4 q2 = W2r[(j) * 8 + 2]; \
    const float4 q3 = W2r[(j) * 8 + 3]; \
    const float4 q4 = W2r[(j) * 8 + 4]; \
    const float4 q5 = W2r[(j) * 8 + 5]; \
    const float4 q6 = W2r[(j) * 8 + 6]; \
    const float4 q7 = W2r[(j) * 8 + 7]; \
    f32x2 zza = {B2[j], 0.0f}; \
    f32x2 zzb = {0.0f, 0.0f}; \
    zza += (f32x2){q0.x, q0.x} * at0;  zzb += (f32x2){q0.y, q0.y} * at1; \
    zza += (f32x2){q0.z, q0.z} * at2;  zzb += (f32x2){q0.w, q0.w} * at3; \
    zza += (f32x2){q1.x, q1.x} * at4;  zzb += (f32x2){q1.y, q1.y} * at5; \
    zza += (f32x2){q1.z, q1.z} * at6;  zzb += (f32x2){q1.w, q1.w} * at7; \
    zza += (f32x2){q2.x, q2.x} * at8;  zzb += (f32x2){q2.y, q2.y} * at9; \
    zza += (f32x2){q2.z, q2.z} * at10; zzb += (f32x2){q2.w, q2.w} * at11; \
    zza += (f32x2){q3.x, q3.x} * at12; zzb += (f32x2){q3.y, q3.y} * at13; \
    zza += (f32x2){q3.z, q3.z} * at14; zzb += (f32x2){q3.w, q3.w} * at15; \
    zza += (f32x2){q4.x, q4.x} * at16; zzb += (f32x2){q4.y, q4.y} * at17; \
    zza += (f32x2){q4.z, q4.z} * at18; zzb += (f32x2){q4.w, q4.w} * at19; \
    zza += (f32x2){q5.x, q5.x} * at20; zzb += (f32x2){q5.y, q5.y} * at21; \
    zza += (f32x2){q5.z, q5.z} * at22; zzb += (f32x2){q5.w, q5.w} * at23; \
    zza += (f32x2){q6.x, q6.x} * at24; zzb += (f32x2){q6.y, q6.y} * at25; \
    zza += (f32x2){q6.z, q6.z} * at26; zzb += (f32x2){q6.w, q6.w} * at27; \
    zza += (f32x2){q7.x, q7.x} * at28; zzb += (f32x2){q7.y, q7.y} * at29; \
    zza += (f32x2){q7.z, q7.z} * at30; zzb += (f32x2){q7.w, q7.w} * at31; \
    const f32x2 zzt = zza + zzb; \
    const float zv  = zzt.x; \
    const float sg  = sigmoidf_fast(zv); \
    const float da  = sg * (1.0f + zv * (1.0f - sg)); \
    const float w3  = W3r[j]; \
    acc2 += (f32x2){w3, w3} * (f32x2){zv * sg, da * zzt.y}; \
}

// ---------------------------------------------------------------------------
// Kernel 1a: evaluate packed half2{h, q} at standardized grid points.
// Row st uses s = 2^(mu + (k*DZ - 8)*sd), mu = MU_C*t, sd = SD_C*sqrt(t)+eps.
// q = s * dh/ds (O(1..1e4)-bounded, fp16-safe; exactly what Milstein needs).
// Single MLP_BODY per thread -> no spill (R9's lane-255 trick caused VGPR=256).
// ---------------------------------------------------------------------------
__global__ __launch_bounds__(256) void table_eval_kernel(
    const float* __restrict__ ts,
    const float* __restrict__ W1, const float* __restrict__ b1,
    const float* __restrict__ W2, const float* __restrict__ b2,
    const float* __restrict__ W3, const float* __restrict__ b3,
    unsigned int* __restrict__ A)
{
    __shared__ __align__(16) float sW1[64];
    __shared__ float sb1[32];
    __shared__ __align__(16) float sW2[1024];
    __shared__ float sb2[32];
    __shared__ float sW3[32];
    __shared__ float sb3[1];

    const int tid = threadIdx.x;
    for (int i = tid; i < 1024; i += 256) sW2[i] = W2[i];
    if (tid < 64) sW1[tid] = W1[tid];
    if (tid < 32) { sb1[tid] = b1[tid]; sb2[tid] = b2[tid]; sW3[tid] = W3[tid]; }
    if (tid == 0) sb3[0] = b3[0];
    __syncthreads();

    const float2* W1r = (const float2*)sW1;
    const float*  B1  = sb1;
    const float4* W2r = (const float4*)sW2;
    const float*  B2  = sb2;
    const float*  W3r = sW3;
    const float   b3v = sb3[0];

    const int gid = blockIdx.x * 256 + tid;
    const int st = gid >> LGN;
    const int k  = gid & (NPTS - 1);

    const float t  = ts[st];
    const float mu = MU_C * t;
    const float sd = SD_C * __builtin_sqrtf(t) + 1e-4f;
    const float zz = fmaf((float)k, DZ, -8.0f);
    const float s  = __builtin_amdgcn_exp2f(fmaf(zz, sd, mu));

    float h, hacc;
    MLP_BODY(W1r, B1, W2r, B2, W3r, b3v, t, s, 1.0f, h, hacc)

    const float q = h * (1.0f - h) * hacc * s;   // s * dh/ds
    __half2 p = __floats2half2_rn(h, q);
    A[gid] = *(unsigned int*)&p;
}

// ---------------------------------------------------------------------------
// Kernel 1b: pure-memory pair pack: T2[st][k] = {A[st][k], A[st][k+1]}
// (clamped at row end; i0 can reach NPTS-1 only via the query clamp, and the
// duplicated entry makes that safe).
// ---------------------------------------------------------------------------
__global__ __launch_bounds__(256) void pack_kernel(
    const unsigned int* __restrict__ A, uint2* __restrict__ T2)
{
    const int gid = blockIdx.x * 256 + threadIdx.x;
    const int k = gid & (NPTS - 1);
    const unsigned int a = A[gid];
    const unsigned int b = A[gid + (k < NPTS - 1 ? 1 : 0)];
    T2[gid] = make_uint2(a, b);
}

// ---------------------------------------------------------------------------
// Kernel 2: SDE path integration. 16-step chunks, s-recurrence runs ahead,
// 16 paired 8B gathers + 16 noise prefetches in flight. Standardized-z
// indexing keeps a wave's gathers within ~8 cache lines.
// ---------------------------------------------------------------------------
__global__ __launch_bounds__(256, 2) void path_kernel(
    const float* __restrict__ noise,   // (NSTEPS, BATCH)
    const float* __restrict__ ts,      // (NSTEPS+1)
    const float* __restrict__ wq,      // scalar
    const uint2* __restrict__ T2,      // (NSTEPS, NPTS) paired entries
    float* __restrict__ out)           // (BATCH)
{
    __shared__ float4 sdt4[NSTEPS];    // {dt, sqrt(dt), mu, 1/sd}
    const int tid = threadIdx.x;
    if (tid < NSTEPS) {
        const float t0  = ts[tid];
        const float dtv = ts[tid + 1] - t0;
        const float sdv = SD_C * __builtin_sqrtf(t0) + 1e-4f;
        sdt4[tid] = make_float4(dtv, __builtin_sqrtf(dtv),
                                MU_C * t0, fast_rcp(sdv));
    }
    __syncthreads();

    const int gid = blockIdx.x * 256 + tid;
    const float* np_ = noise + gid;
    const float umax = (float)NPTS - 1.001f;

    float s   = 1.0f;
    float pnl = 0.0f;

    // preload chunk 0 noise (16 values)
    #define NLD0(k) float n##k = np_[(size_t)(k) * BATCH];
    REP16(NLD0)
    #undef NLD0

    #pragma unroll 1
    for (int c = 0; c < NSTEPS / 16; ++c) {
        const int base = c * 16;

        // prefetch next chunk's noise (uniform branch, loads issued early)
        const float* nb = np_ + ((size_t)base + 16) * BATCH;
        #define NDCL(k) float m##k;
        REP16(NDCL)
        #undef NDCL
        if (c < NSTEPS / 16 - 1) {
            #define NPF(k) m##k = nb[(size_t)(k) * BATCH];
            REP16(NPF)
            #undef NPF
        } else {
            #define NZR(k) m##k = 0.0f;
            REP16(NZR)
            #undef NZR
        }

        // s-chain (cheap, serial) + issue all 16 paired gathers
        #define CH(k) \
            const float4 dq##k = sdt4[base + k]; \
            const float dW##k   = n##k * dq##k.y; \
            const float mil##k  = 0.5f * fmaf(dW##k, dW##k, -dq##k.x); \
            const float sum1##k = dq##k.x + dW##k; \
            const float sv##k   = s; \
            s = fmaf(s, sum1##k + mil##k, s); \
            const float x##k = __builtin_amdgcn_logf(sv##k); \
            const float u##k = fminf(fmaxf( \
                fmaf(x##k - dq##k.z, dq##k.w, 8.0f) * ZSCALE, 0.0f), umax); \
            const int   i0##k = (int)u##k; \
            const float f##k  = u##k - (float)i0##k; \
            const uint2 E##k = T2[((size_t)(base + k) << LGN) + i0##k];
        REP16(CH)
        #undef CH

        // consume gathers into pnl
        #define PN(k) { \
            const float2 a0 = __half22float2(*(const __half2*)&E##k.x); \
            const float2 a1 = __half22float2(*(const __half2*)&E##k.y); \
            const float h  = fmaf(f##k, a1.x - a0.x, a0.x); \
            const float q  = fmaf(f##k, a1.y - a0.y, a0.y); \
            const float g1  = sv##k * h; \
            const float dg1 = fmaf(sv##k, q, g1); \
            pnl = fmaf(dg1, mil##k, fmaf(g1, sum1##k, pnl)); }
        REP16(PN)
        #undef PN

        // rotate prefetched noise into place
        #define NRT(k) n##k = m##k;
        REP16(NRT)
        #undef NRT
    }

    const float z = fmaxf(0.0f, s - 3.0f);
    const float d = z - pnl - wq[0];
    out[gid] = d * d;
}

// ---------------------------------------------------------------------------
// Fallback: direct per-thread MLP evaluation (R4 kernel) if ws too small.
// ---------------------------------------------------------------------------
__global__ __launch_bounds__(256, 3) void deep_hedging_direct(
    const float* __restrict__ noise, const float* __restrict__ ts,
    const float* __restrict__ w,
    const float* __restrict__ W1, const float* __restrict__ b1,
    const float* __restrict__ W2, const float* __restrict__ b2,
    const float* __restrict__ W3, const float* __restrict__ b3,
    float* __restrict__ out)
{
    __shared__ __align__(16) float sW1[64];
    __shared__ float sb1[32];
    __shared__ __align__(16) float sW2[1024];
    __shared__ float sb2[32];
    __shared__ float sW3[32];
    __shared__ float sb3w[2];
    __shared__ float sts[NSTEPS + 1];

    const int tid = threadIdx.x;
    for (int i = tid; i < 1024; i += 256) sW2[i] = W2[i];
    if (tid < 64) sW1[tid] = W1[tid];
    if (tid < 32) { sb1[tid] = b1[tid]; sb2[tid] = b2[tid]; sW3[tid] = W3[tid]; }
    if (tid == 0) { sb3w[0] = b3[0]; sb3w[1] = w[0]; }
    for (int i = tid; i < NSTEPS + 1; i += 256) sts[i] = ts[i];
    __syncthreads();

    const int gid = blockIdx.x * 256 + tid;
    const float* np_ = noise + gid;

    float s   = 1.0f;
    float pnl = 0.0f;
    const float b3v = sb3w[0];
    const float wv_ = sb3w[1];

    #pragma unroll 1
    for (int st = 0; st < NSTEPS; ++st) {
        int zr = 0;
        asm volatile("" : "+v"(zr));   // block LICM of weight loads
        const float2* W1r = (const float2*)sW1 + zr;
        const float*  B1  = sb1 + zr;
        const float4* W2r = (const float4*)sW2 + zr;
        const float*  B2  = sb2 + zr;
        const float*  W3r = sW3 + zr;

        const float t  = sts[st];
        const float dt = sts[st + 1] - t;
        const float dW = np_[(size_t)st * BATCH] * __builtin_sqrtf(dt);
        const float sd = s;

        float h, hacc;
        MLP_BODY(W1r, B1, W2r, B2, W3r, b3v, t, s, sd, h, hacc)
        const float hd = h * (1.0f - h) * hacc;

        const float mil = 0.5f * (dW * dW - dt);
        const float g1  = s * h;
        const float dg1 = fmaf(sd, h, s * hd);
        const float snew = s + s * dt + s * dW + sd * mil;
        pnl = pnl + g1 * dt + g1 * dW + dg1 * mil;
        s = snew;
    }

    const float z = fmaxf(0.0f, s - 3.0f);
    const float d = z - pnl - wv_;
    out[gid] = d * d;
}

extern "C" void kernel_launch(void* const* d_in, const int* in_sizes, int n_in,
                              void* d_out, int out_size, void* d_ws, size_t ws_size,
                              hipStream_t stream) {
    const float* noise = (const float*)d_in[0];
    const float* ts    = (const float*)d_in[1];
    const float* w     = (const float*)d_in[2];
    const float* W1    = (const float*)d_in[3];
    const float* b1    = (const float*)d_in[4];
    const float* W2    = (const float*)d_in[5];
    const float* b2    = (const float*)d_in[6];
    const float* W3    = (const float*)d_in[7];
    const float* b3    = (const float*)d_in[8];
    float* out = (float*)d_out;

    const size_t nA   = (size_t)NSTEPS * NPTS;            // entries
    const size_t need = nA * (sizeof(unsigned int) + sizeof(uint2));  // 3 MB

    if (ws_size >= need) {
        unsigned int* A = (unsigned int*)d_ws;
        uint2* T2 = (uint2*)((char*)d_ws + nA * sizeof(unsigned int));

        dim3 tb(256), tg(nA / 256);
        table_eval_kernel<<<tg, tb, 0, stream>>>(ts, W1, b1, W2, b2, W3, b3, A);
        pack_kernel<<<tg, tb, 0, stream>>>(A, T2);
        dim3 pb(256), pg(BATCH / 256);
        path_kernel<<<pg, pb, 0, stream>>>(noise, ts, w, T2, out);
    } else {
        dim3 grid(BATCH / 256), block(256);
        deep_hedging_direct<<<grid, block, 0, stream>>>(noise, ts, w, W1, b1,
                                                        W2, b2, W3, b3, out);
    }
}